// Round 17
// baseline (173.247 us; speedup 1.0000x reference)
//
#include <hip/hip_runtime.h>

// SNN spike layer: causal alpha-PSP FIR conv (taps 1..76; srm[0]==0 exactly)
// + sequential refractory threshold scan.
//
// Round-17: coalesce the fused kernel's read stream. R16 (fused pack+flag+
// zero, 149.9us total) profiled at 2.3 TB/s / VALU 9.4%: phase A had each
// THREAD read 128B contiguous -> lanes 128B apart -> every dwordx4 was a
// 64-line gather (8x read-transaction amplification). This build packs via
// BALLOT: wave reads 64 consecutive floats per instruction (256B coalesced),
// 5 independent loads/iter for MLP; lanes 0/1 write the two bit-words to
// LDS. Bit layout in Wlds is IDENTICAL (word w = floats [32w,32w+32)), so
// phase B (funnel + 299-step IIR upper bound) and scan_fix are unchanged.
//
// Structure:
//   fused_kernel : block = 64 neurons; phase A ballot-pack to LDS +
//     coalesced zero-store of the group's output; phase B (threads 0..63)
//     per-row IIR upper bound -> flags. HBM = read 78.6 + write 78.9 MB.
//   scan_fix     : flagged rows -> verified R10 event-driven conv +
//     sequential scan (exact).  ws = flags only (256 KB).
//   fallback     : verified R10 single kernel (ws too small).
//
// Exactness theorem (all inputs): srm[j] = c*j*rho^j (c=e/10, rho=e^-0.1);
// A[t]=rho*(A[t-1]+x[t-1]), D[t]=rho*D[t-1]+A[t] => c*D[t] = untruncated
// conv >= u_true[t] (all terms >= 0). Ref tail rt[] <= 0 => pend <= 0 =>
// u_eff <= u_true <= c*D. Unflagged (c*dmax < 9 < theta) => no spike =>
// zeros exact. Model guard: all 77 taps checked vs model (tol 2e-3) and
// srm_len==77; mismatch -> flag ALL -> scan_fix recomputes exactly.

#define T_LEN 300
#define CH 20
#define NCHUNK 15
#define KS 77              // srm kernel length (alpha, tau=10, eps_tol=0.01)
#define KR 10              // ref kernel tail length (K_ref=11 -> 10 pending)
#define THETA_V 10.0f
#define TSZ 115            // scan_fix gather table: idx = 95 + c - p

#define RHO_F   0.9048374180359596f   // exp(-0.1)
#define C_E10   0.2718281828459045f   // e/10
#define THR_D   (9.0f / C_E10)        // flag iff D >= 9/c
#define TAP_TOL 2e-3f

#define NPB  64            // neurons per group/block
#define WPG  600           // bit-words per group: 64*300/32
#define GPB  300           // 64-float ballot groups per block
#define F4PG 4800          // float4s per group: 64*300/4

// -------- fused: ballot-pack (LDS) + IIR flag + coalesced zero-store -------
__global__ __launch_bounds__(256) void fused_kernel(
    const float* __restrict__ spike_in,
    const float* __restrict__ srm, int srm_len,
    float* __restrict__ out, unsigned* __restrict__ flags, int B)
{
    __shared__ unsigned Wlds[WPG + 8];

    const int t    = threadIdx.x;
    const int wv   = t >> 6;                      // wave 0..3
    const int lane = t & 63;
    const int g    = blockIdx.x;                  // neuron group
    const long long NF     = (long long)B * T_LEN;
    const long long base_f = (long long)NPB * T_LEN * g;   // 19200*g

    // ---- phase A: ballot-pack. Wave wv handles groups [75wv, 75wv+75).
    // Each instruction reads 64 CONSECUTIVE floats (256B coalesced); 5
    // independent loads per iteration for MLP. Bit L of ballot = lane L
    // = float (64*gl + L): Wlds layout identical to R16 (verified).
#pragma unroll 3
    for (int k = 0; k < 15; ++k) {
        unsigned long long m0, m1, m2, m3, m4;
        {
            const int gl = 75 * wv + 5 * k;
            const long long f = base_f + 64LL * gl + lane;
            float x0 = (f           < NF) ? spike_in[f]           : 0.0f;
            float x1 = (f + 64      < NF) ? spike_in[f + 64]      : 0.0f;
            float x2 = (f + 128     < NF) ? spike_in[f + 128]     : 0.0f;
            float x3 = (f + 192     < NF) ? spike_in[f + 192]     : 0.0f;
            float x4 = (f + 256     < NF) ? spike_in[f + 256]     : 0.0f;
            m0 = __ballot(x0 != 0.0f);
            m1 = __ballot(x1 != 0.0f);
            m2 = __ballot(x2 != 0.0f);
            m3 = __ballot(x3 != 0.0f);
            m4 = __ballot(x4 != 0.0f);
        }
        const int gl0 = 75 * wv + 5 * k;
        if (lane == 0) {
            Wlds[2 * gl0 + 0] = (unsigned)m0;
            Wlds[2 * gl0 + 2] = (unsigned)m1;
            Wlds[2 * gl0 + 4] = (unsigned)m2;
            Wlds[2 * gl0 + 6] = (unsigned)m3;
            Wlds[2 * gl0 + 8] = (unsigned)m4;
        } else if (lane == 1) {
            Wlds[2 * gl0 + 1] = (unsigned)(m0 >> 32);
            Wlds[2 * gl0 + 3] = (unsigned)(m1 >> 32);
            Wlds[2 * gl0 + 5] = (unsigned)(m2 >> 32);
            Wlds[2 * gl0 + 7] = (unsigned)(m3 >> 32);
            Wlds[2 * gl0 + 9] = (unsigned)(m4 >> 32);
        }
    }
    if (t < 8) Wlds[WPG + t] = 0u;                // funnel-read slack

    // ---- phase A: coalesced zero-store of the group's output region -------
    {
        const float4 z = make_float4(0.0f, 0.0f, 0.0f, 0.0f);
        const long long nf4 = NF >> 2;
        float4* o4 = (float4*)out;
#pragma unroll
        for (int k = 0; k < 19; ++k) {            // 19*256 >= 4800
            const int lw = t + 256 * k;
            if (lw < F4PG) {
                const long long i4 = (long long)F4PG * g + lw;
                if (i4 < nf4) o4[i4] = z;
            }
        }
    }

    __syncthreads();

    // ---- phase B: IIR upper bound, one thread per neuron (verified code) --
    if (t < NPB) {
        const long long neuron = (long long)NPB * g + t;
        if (neuron < B) {
            // model guard: srm must match c*j*rho^j within TAP_TOL.
            bool ok = (srm_len == KS);
            if (ok) {
                ok = fabsf(srm[0]) <= TAP_TOL;
                float pj = 1.0f;
                for (int j = 1; j < KS; ++j) {
                    pj *= RHO_F;
                    float mj = C_E10 * (float)j * pj;
                    ok = ok && (fabsf(srm[j] - mj) <= TAP_TOL);
                }
            }

            // assemble row bits: row t covers group bits [300t, 300t+300)
            const int F0 = T_LEN * t;
            const int q = F0 >> 5;
            const int r = F0 & 31;
            unsigned W[11];
#pragma unroll
            for (int k = 0; k < 11; ++k) W[k] = Wlds[q + k];
            unsigned aw[10];                      // aw[k] bit b = row bit 32k+b
#pragma unroll
            for (int k = 0; k < 10; ++k)
                aw[k] = (unsigned)((((unsigned long long)W[k + 1] << 32) | W[k]) >> r);

            // IIR: A[t]=rho*(A[t-1]+x[t-1]); D[t]=rho*D[t-1]+A[t]
            float A = 0.0f, D = 0.0f, dmax = 0.0f;
#pragma unroll
            for (int tt = 1; tt < T_LEN; ++tt) {
                const int bw = (tt - 1) >> 5;     // compile-time
                const int bb = (tt - 1) & 31;     // compile-time
                int ms = ((int)(aw[bw] << (31 - bb))) >> 31;
                float xr = __int_as_float(ms & __float_as_int(RHO_F));
                A = fmaf(RHO_F, A, xr);
                D = fmaf(RHO_F, D, A);
                dmax = fmaxf(dmax, D);
            }

            flags[neuron] = (!ok || (dmax >= THR_D)) ? 1u : 0u;
        }
    }
}

// ------------- scan_fix: flagged rows -> verified exact recompute ----------
__global__ __launch_bounds__(256) void scan_fix_kernel(
    const float* __restrict__ spike_in,
    const float* __restrict__ srm, int srm_len,
    const float* __restrict__ refk, int ref_len,
    float* __restrict__ out, const unsigned* __restrict__ flags, int B)
{
    __shared__ float T[TSZ + 13];
    {
        int k = threadIdx.x;
        if (k < TSZ + 13) {
            int j = k - 19;
            T[k] = (j >= 1 && j < KS && j < srm_len) ? srm[j] : 0.0f;
        }
    }
    __syncthreads();

    int b = blockIdx.x * blockDim.x + threadIdx.x;
    if (b >= B) return;
    if (flags[b] == 0u) return;     // zeros from fused are exact

    const float* row  = spike_in + (size_t)b * T_LEN;
    float*       orow = out      + (size_t)b * T_LEN;

    float rt[KR];
#pragma unroll
    for (int i = 0; i < KR; ++i) rt[i] = (i + 1 < ref_len) ? refk[i + 1] : 0.0f;
    float pend[KR];
#pragma unroll
    for (int i = 0; i < KR; ++i) pend[i] = 0.0f;

    unsigned w0 = 0, w1 = 0, w2 = 0;
    float nxt[CH];
    {
        const float4* p = (const float4*)row;
#pragma unroll
        for (int i = 0; i < CH / 4; ++i) {
            float4 v = p[i];
            nxt[4*i+0] = v.x; nxt[4*i+1] = v.y; nxt[4*i+2] = v.z; nxt[4*i+3] = v.w;
        }
    }

#pragma unroll 1
    for (int ch = 0; ch < NCHUNK; ++ch) {
        unsigned nb = 0;
#pragma unroll
        for (int i = 0; i < CH; ++i)
            nb |= (nxt[i] != 0.0f) ? (1u << i) : 0u;

        w0 = (w0 >> 20) | (w1 << 12);
        w1 = (w1 >> 20) | (w2 << 12);
        w2 = (w2 >> 20) | (nb << 12);

        if (ch + 1 < NCHUNK) {
            const float4* p = (const float4*)(row + (ch + 1) * CH);
#pragma unroll
            for (int i = 0; i < CH / 4; ++i) {
                float4 v = p[i];
                nxt[4*i+0] = v.x; nxt[4*i+1] = v.y; nxt[4*i+2] = v.z; nxt[4*i+3] = v.w;
            }
        }
        __builtin_amdgcn_sched_barrier(0);

        float u[CH];
#pragma unroll
        for (int c = 0; c < CH; ++c) u[c] = 0.0f;

        unsigned a0 = w0, a1 = w1, a2 = w2;
        while (__ballot(a0 | a1 | a2)) {
            int p = a2 ? (95 - __clz(a2))
                       : (a1 ? (63 - __clz(a1))
                             : (a0 ? (31 - __clz(a0)) : 95));
            unsigned m = 1u << (p & 31);
            if (p >= 64)      a2 &= ~m;
            else if (p >= 32) a1 &= ~m;
            else              a0 &= ~m;

            const float* tp = &T[95 - p];
#pragma unroll
            for (int c = 0; c < CH; ++c)
                u[c] += tp[c];          // == fmaf(srm[j], 1.0f, u[c])
        }

        float so[CH];
#pragma unroll
        for (int c = 0; c < CH; ++c) {
            const int r = c % KR;
            float u_eff = u[c] + pend[r];
            float s = (u_eff >= THETA_V) ? 1.0f : 0.0f;
#pragma unroll
            for (int i = 0; i < KR - 1; ++i)
                pend[(r + 1 + i) % KR] = fmaf(s, rt[i], pend[(r + 1 + i) % KR]);
            pend[r] = s * rt[KR - 1];
            so[c] = s;
        }

        float4* op = (float4*)(orow + ch * CH);
#pragma unroll
        for (int i = 0; i < CH / 4; ++i) {
            float4 v;
            v.x = so[4*i+0]; v.y = so[4*i+1]; v.z = so[4*i+2]; v.w = so[4*i+3];
            op[i] = v;
        }
    }
}

// --------- fallback: round-10 single-kernel path (ws too small) ------------
__global__ __launch_bounds__(256)
__attribute__((amdgpu_waves_per_eu(1, 1)))
void spike_layer_kernel(
    const float* __restrict__ spike_in,
    const float* __restrict__ srm, int srm_len,
    const float* __restrict__ refk, int ref_len,
    float* __restrict__ out, int B)
{
    __shared__ float T[TSZ + 13];
    {
        int k = threadIdx.x;
        if (k < TSZ + 13) {
            int j = k - 19;
            T[k] = (j >= 1 && j < KS && j < srm_len) ? srm[j] : 0.0f;
        }
    }
    __syncthreads();

    int b = blockIdx.x * blockDim.x + threadIdx.x;
    if (b >= B) return;

    const float* row  = spike_in + (size_t)b * T_LEN;
    float*       orow = out      + (size_t)b * T_LEN;

    float rt[KR];
#pragma unroll
    for (int i = 0; i < KR; ++i) rt[i] = (i + 1 < ref_len) ? refk[i + 1] : 0.0f;
    float pend[KR];
#pragma unroll
    for (int i = 0; i < KR; ++i) pend[i] = 0.0f;

    unsigned w0 = 0, w1 = 0, w2 = 0;
    float nxt[CH];
    {
        const float4* p = (const float4*)row;
#pragma unroll
        for (int i = 0; i < CH / 4; ++i) {
            float4 v = p[i];
            nxt[4*i+0] = v.x; nxt[4*i+1] = v.y; nxt[4*i+2] = v.z; nxt[4*i+3] = v.w;
        }
    }

#pragma unroll 1
    for (int ch = 0; ch < NCHUNK; ++ch) {
        unsigned nb = 0;
#pragma unroll
        for (int i = 0; i < CH; ++i)
            nb |= (nxt[i] != 0.0f) ? (1u << i) : 0u;

        w0 = (w0 >> 20) | (w1 << 12);
        w1 = (w1 >> 20) | (w2 << 12);
        w2 = (w2 >> 20) | (nb << 12);

        if (ch + 1 < NCHUNK) {
            const float4* p = (const float4*)(row + (ch + 1) * CH);
#pragma unroll
            for (int i = 0; i < CH / 4; ++i) {
                float4 v = p[i];
                nxt[4*i+0] = v.x; nxt[4*i+1] = v.y; nxt[4*i+2] = v.z; nxt[4*i+3] = v.w;
            }
        }
        __builtin_amdgcn_sched_barrier(0);

        float u[CH];
#pragma unroll
        for (int c = 0; c < CH; ++c) u[c] = 0.0f;

        unsigned a0 = w0, a1 = w1, a2 = w2;
        while (__ballot(a0 | a1 | a2)) {
            int p = a2 ? (95 - __clz(a2))
                       : (a1 ? (63 - __clz(a1))
                             : (a0 ? (31 - __clz(a0)) : 95));
            unsigned m = 1u << (p & 31);
            if (p >= 64)      a2 &= ~m;
            else if (p >= 32) a1 &= ~m;
            else              a0 &= ~m;

            const float* tp = &T[95 - p];
#pragma unroll
            for (int c = 0; c < CH; ++c)
                u[c] += tp[c];
        }

        float so[CH];
#pragma unroll
        for (int c = 0; c < CH; ++c) {
            const int r = c % KR;
            float u_eff = u[c] + pend[r];
            float s = (u_eff >= THETA_V) ? 1.0f : 0.0f;
#pragma unroll
            for (int i = 0; i < KR - 1; ++i)
                pend[(r + 1 + i) % KR] = fmaf(s, rt[i], pend[(r + 1 + i) % KR]);
            pend[r] = s * rt[KR - 1];
            so[c] = s;
        }

        float4* op = (float4*)(orow + ch * CH);
#pragma unroll
        for (int i = 0; i < CH / 4; ++i) {
            float4 v;
            v.x = so[4*i+0]; v.y = so[4*i+1]; v.z = so[4*i+2]; v.w = so[4*i+3];
            op[i] = v;
        }
    }
}

extern "C" void kernel_launch(void* const* d_in, const int* in_sizes, int n_in,
                              void* d_out, int out_size, void* d_ws, size_t ws_size,
                              hipStream_t stream) {
    const float* spike_in = (const float*)d_in[0];
    const float* srm      = (const float*)d_in[1];
    const float* refk     = (const float*)d_in[2];
    float* out = (float*)d_out;

    int srm_len = in_sizes[1];
    int ref_len = in_sizes[2];
    int B = in_sizes[0] / T_LEN;   // 65536 neurons

    const size_t need = (size_t)B * sizeof(unsigned);   // flags only: 256 KB

    if (d_ws != nullptr && ws_size >= need) {
        unsigned* flags = (unsigned*)d_ws;
        const int groups = (B + NPB - 1) / NPB;          // 1024
        fused_kernel<<<groups, 256, 0, stream>>>(spike_in, srm, srm_len,
                                                 out, flags, B);
        scan_fix_kernel<<<(B + 255) / 256, 256, 0, stream>>>(
            spike_in, srm, srm_len, refk, ref_len, out, flags, B);
    } else {
        int grid = (B + 255) / 256;
        spike_layer_kernel<<<grid, 256, 0, stream>>>(spike_in, srm, srm_len,
                                                     refk, ref_len, out, B);
    }
}

// Round 18
// 149.826 us; speedup vs baseline: 1.1563x; 1.1563x over previous
//
#include <hip/hip_runtime.h>

// SNN spike layer: causal alpha-PSP FIR conv (taps 1..76; srm[0]==0 exactly)
// + sequential refractory threshold scan.
//
// Round-18: fix the fused kernel's read path with BOTH full-line coalescing
// AND deep MLP (R16 had MLP but 16B-of-128B line use -> L1 thrash, 2.3TB/s;
// R17 had coalescing but 256B/instr + ballot syncs -> no MLP, 1.6TB/s).
//   phase A: thread loads float4 at lane-consecutive index (1KB/instr fully
//     coalesced; 19 independent loads/thread), packs 4 bool-bytes into one
//     u32, writes LDS at i4+(i4>>3) (pad word per 8 -> 2-way banks = free).
//     Zero-store of the group's output unchanged (WRITE already ideal).
//   barrier; pack: word w = 8 LDS u32s -> nibbles via
//     (v|v>>7|v>>14|v>>21)&0xF -> Wlds[w]. Bit layout IDENTICAL to R16
//     (word w = floats [32w,32w+32), bit = float offset).
//   barrier; phase B: per-row funnel + 299-step IIR upper bound (verified,
//     unchanged) -> flags.
//   scan_fix: flagged rows -> verified R10 event-driven conv + sequential
//     scan (exact). ws = flags only (256 KB). Fallback: verified R10.
//
// Exactness theorem (all inputs): srm[j] = c*j*rho^j (c=e/10, rho=e^-0.1);
// A[t]=rho*(A[t-1]+x[t-1]), D[t]=rho*D[t-1]+A[t] => c*D[t] = untruncated
// conv >= u_true[t] (all terms >= 0). Ref tail rt[] <= 0 => pend <= 0 =>
// u_eff <= u_true <= c*D. Unflagged (c*dmax < 9 < theta) => no spike =>
// zeros exact. Model guard: all 77 taps checked vs model (tol 2e-3) and
// srm_len==77; mismatch -> flag ALL -> scan_fix recomputes exactly.

#define T_LEN 300
#define CH 20
#define NCHUNK 15
#define KS 77              // srm kernel length (alpha, tau=10, eps_tol=0.01)
#define KR 10              // ref kernel tail length (K_ref=11 -> 10 pending)
#define THETA_V 10.0f
#define TSZ 115            // scan_fix gather table: idx = 95 + c - p

#define RHO_F   0.9048374180359596f   // exp(-0.1)
#define C_E10   0.2718281828459045f   // e/10
#define THR_D   (9.0f / C_E10)        // flag iff D >= 9/c
#define TAP_TOL 2e-3f

#define NPB  64            // neurons per group/block
#define WPG  600           // bit-words per group: 64*300/32
#define F4PG 4800          // float4s per group: 64*300/4
#define SW   5400          // stage u32s: 4800 + 4800/8 pad

// -------- fused: coalesced bool-byte stage + pack + IIR flag + zeros -------
__global__ __launch_bounds__(256) void fused_kernel(
    const float* __restrict__ spike_in,
    const float* __restrict__ srm, int srm_len,
    float* __restrict__ out, unsigned* __restrict__ flags, int B)
{
    __shared__ unsigned stage[SW];                // 21.6 KB bool-byte stage
    __shared__ unsigned Wlds[WPG + 8];            // 2.4 KB bit-words

    const int t = threadIdx.x;
    const int g = blockIdx.x;                     // neuron group
    const long long NF     = (long long)B * T_LEN;
    const long long base_4 = (long long)F4PG * g; // group's first float4

    // ---- phase A: lane-consecutive float4 loads (1KB/instr coalesced),
    // 19 independent per thread; pack 4 bool-bytes -> 1 u32 -> LDS. --------
#pragma unroll
    for (int k = 0; k < 19; ++k) {
        const int i4 = t + 256 * k;
        if (i4 < F4PG) {
            const long long f4 = base_4 + i4;
            unsigned pk = 0u;
            if (4 * f4 + 4 <= NF) {               // NF divisible by 4
                float4 v = ((const float4*)spike_in)[f4];
                pk  = (v.x != 0.0f ? 1u : 0u);
                pk |= (v.y != 0.0f ? 1u : 0u) << 8;
                pk |= (v.z != 0.0f ? 1u : 0u) << 16;
                pk |= (v.w != 0.0f ? 1u : 0u) << 24;
            }
            stage[i4 + (i4 >> 3)] = pk;           // pad/8 -> 2-way banks
        }
    }

    // ---- phase A: coalesced zero-store of the group's output region -------
    {
        const float4 z = make_float4(0.0f, 0.0f, 0.0f, 0.0f);
        const long long nf4 = NF >> 2;
        float4* o4 = (float4*)out;
#pragma unroll
        for (int k = 0; k < 19; ++k) {            // 19*256 >= 4800
            const int lw = t + 256 * k;
            if (lw < F4PG) {
                const long long i4 = base_4 + lw;
                if (i4 < nf4) o4[i4] = z;
            }
        }
    }

    __syncthreads();

    // ---- pack: word w = quads 8w..8w+7 (stage idx 9w+i); nibble trick ----
#pragma unroll
    for (int k = 0; k < 3; ++k) {
        const int w = t + 256 * k;
        if (w < WPG) {
            unsigned bits = 0u;
#pragma unroll
            for (int i = 0; i < 8; ++i) {
                unsigned v = stage[9 * w + i];    // bank (9w+i)%32: 2-way
                v = (v | (v >> 7) | (v >> 14) | (v >> 21)) & 0xFu;
                bits |= v << (4 * i);
            }
            Wlds[w] = bits;                       // layout identical to R16
        }
    }
    if (t < 8) Wlds[WPG + t] = 0u;                // funnel-read slack

    __syncthreads();

    // ---- phase B: IIR upper bound, one thread per neuron (verified code) --
    if (t < NPB) {
        const long long neuron = (long long)NPB * g + t;
        if (neuron < B) {
            // model guard: srm must match c*j*rho^j within TAP_TOL.
            bool ok = (srm_len == KS);
            if (ok) {
                ok = fabsf(srm[0]) <= TAP_TOL;
                float pj = 1.0f;
                for (int j = 1; j < KS; ++j) {
                    pj *= RHO_F;
                    float mj = C_E10 * (float)j * pj;
                    ok = ok && (fabsf(srm[j] - mj) <= TAP_TOL);
                }
            }

            // assemble row bits: row t covers group bits [300t, 300t+300)
            const int F0 = T_LEN * t;
            const int q = F0 >> 5;
            const int r = F0 & 31;
            unsigned W[11];
#pragma unroll
            for (int k = 0; k < 11; ++k) W[k] = Wlds[q + k];
            unsigned aw[10];                      // aw[k] bit b = row bit 32k+b
#pragma unroll
            for (int k = 0; k < 10; ++k)
                aw[k] = (unsigned)((((unsigned long long)W[k + 1] << 32) | W[k]) >> r);

            // IIR: A[t]=rho*(A[t-1]+x[t-1]); D[t]=rho*D[t-1]+A[t]
            float A = 0.0f, D = 0.0f, dmax = 0.0f;
#pragma unroll
            for (int tt = 1; tt < T_LEN; ++tt) {
                const int bw = (tt - 1) >> 5;     // compile-time
                const int bb = (tt - 1) & 31;     // compile-time
                int ms = ((int)(aw[bw] << (31 - bb))) >> 31;
                float xr = __int_as_float(ms & __float_as_int(RHO_F));
                A = fmaf(RHO_F, A, xr);
                D = fmaf(RHO_F, D, A);
                dmax = fmaxf(dmax, D);
            }

            flags[neuron] = (!ok || (dmax >= THR_D)) ? 1u : 0u;
        }
    }
}

// ------------- scan_fix: flagged rows -> verified exact recompute ----------
__global__ __launch_bounds__(256) void scan_fix_kernel(
    const float* __restrict__ spike_in,
    const float* __restrict__ srm, int srm_len,
    const float* __restrict__ refk, int ref_len,
    float* __restrict__ out, const unsigned* __restrict__ flags, int B)
{
    __shared__ float T[TSZ + 13];
    {
        int k = threadIdx.x;
        if (k < TSZ + 13) {
            int j = k - 19;
            T[k] = (j >= 1 && j < KS && j < srm_len) ? srm[j] : 0.0f;
        }
    }
    __syncthreads();

    int b = blockIdx.x * blockDim.x + threadIdx.x;
    if (b >= B) return;
    if (flags[b] == 0u) return;     // zeros from fused are exact

    const float* row  = spike_in + (size_t)b * T_LEN;
    float*       orow = out      + (size_t)b * T_LEN;

    float rt[KR];
#pragma unroll
    for (int i = 0; i < KR; ++i) rt[i] = (i + 1 < ref_len) ? refk[i + 1] : 0.0f;
    float pend[KR];
#pragma unroll
    for (int i = 0; i < KR; ++i) pend[i] = 0.0f;

    unsigned w0 = 0, w1 = 0, w2 = 0;
    float nxt[CH];
    {
        const float4* p = (const float4*)row;
#pragma unroll
        for (int i = 0; i < CH / 4; ++i) {
            float4 v = p[i];
            nxt[4*i+0] = v.x; nxt[4*i+1] = v.y; nxt[4*i+2] = v.z; nxt[4*i+3] = v.w;
        }
    }

#pragma unroll 1
    for (int ch = 0; ch < NCHUNK; ++ch) {
        unsigned nb = 0;
#pragma unroll
        for (int i = 0; i < CH; ++i)
            nb |= (nxt[i] != 0.0f) ? (1u << i) : 0u;

        w0 = (w0 >> 20) | (w1 << 12);
        w1 = (w1 >> 20) | (w2 << 12);
        w2 = (w2 >> 20) | (nb << 12);

        if (ch + 1 < NCHUNK) {
            const float4* p = (const float4*)(row + (ch + 1) * CH);
#pragma unroll
            for (int i = 0; i < CH / 4; ++i) {
                float4 v = p[i];
                nxt[4*i+0] = v.x; nxt[4*i+1] = v.y; nxt[4*i+2] = v.z; nxt[4*i+3] = v.w;
            }
        }
        __builtin_amdgcn_sched_barrier(0);

        float u[CH];
#pragma unroll
        for (int c = 0; c < CH; ++c) u[c] = 0.0f;

        unsigned a0 = w0, a1 = w1, a2 = w2;
        while (__ballot(a0 | a1 | a2)) {
            int p = a2 ? (95 - __clz(a2))
                       : (a1 ? (63 - __clz(a1))
                             : (a0 ? (31 - __clz(a0)) : 95));
            unsigned m = 1u << (p & 31);
            if (p >= 64)      a2 &= ~m;
            else if (p >= 32) a1 &= ~m;
            else              a0 &= ~m;

            const float* tp = &T[95 - p];
#pragma unroll
            for (int c = 0; c < CH; ++c)
                u[c] += tp[c];          // == fmaf(srm[j], 1.0f, u[c])
        }

        float so[CH];
#pragma unroll
        for (int c = 0; c < CH; ++c) {
            const int r = c % KR;
            float u_eff = u[c] + pend[r];
            float s = (u_eff >= THETA_V) ? 1.0f : 0.0f;
#pragma unroll
            for (int i = 0; i < KR - 1; ++i)
                pend[(r + 1 + i) % KR] = fmaf(s, rt[i], pend[(r + 1 + i) % KR]);
            pend[r] = s * rt[KR - 1];
            so[c] = s;
        }

        float4* op = (float4*)(orow + ch * CH);
#pragma unroll
        for (int i = 0; i < CH / 4; ++i) {
            float4 v;
            v.x = so[4*i+0]; v.y = so[4*i+1]; v.z = so[4*i+2]; v.w = so[4*i+3];
            op[i] = v;
        }
    }
}

// --------- fallback: round-10 single-kernel path (ws too small) ------------
__global__ __launch_bounds__(256)
__attribute__((amdgpu_waves_per_eu(1, 1)))
void spike_layer_kernel(
    const float* __restrict__ spike_in,
    const float* __restrict__ srm, int srm_len,
    const float* __restrict__ refk, int ref_len,
    float* __restrict__ out, int B)
{
    __shared__ float T[TSZ + 13];
    {
        int k = threadIdx.x;
        if (k < TSZ + 13) {
            int j = k - 19;
            T[k] = (j >= 1 && j < KS && j < srm_len) ? srm[j] : 0.0f;
        }
    }
    __syncthreads();

    int b = blockIdx.x * blockDim.x + threadIdx.x;
    if (b >= B) return;

    const float* row  = spike_in + (size_t)b * T_LEN;
    float*       orow = out      + (size_t)b * T_LEN;

    float rt[KR];
#pragma unroll
    for (int i = 0; i < KR; ++i) rt[i] = (i + 1 < ref_len) ? refk[i + 1] : 0.0f;
    float pend[KR];
#pragma unroll
    for (int i = 0; i < KR; ++i) pend[i] = 0.0f;

    unsigned w0 = 0, w1 = 0, w2 = 0;
    float nxt[CH];
    {
        const float4* p = (const float4*)row;
#pragma unroll
        for (int i = 0; i < CH / 4; ++i) {
            float4 v = p[i];
            nxt[4*i+0] = v.x; nxt[4*i+1] = v.y; nxt[4*i+2] = v.z; nxt[4*i+3] = v.w;
        }
    }

#pragma unroll 1
    for (int ch = 0; ch < NCHUNK; ++ch) {
        unsigned nb = 0;
#pragma unroll
        for (int i = 0; i < CH; ++i)
            nb |= (nxt[i] != 0.0f) ? (1u << i) : 0u;

        w0 = (w0 >> 20) | (w1 << 12);
        w1 = (w1 >> 20) | (w2 << 12);
        w2 = (w2 >> 20) | (nb << 12);

        if (ch + 1 < NCHUNK) {
            const float4* p = (const float4*)(row + (ch + 1) * CH);
#pragma unroll
            for (int i = 0; i < CH / 4; ++i) {
                float4 v = p[i];
                nxt[4*i+0] = v.x; nxt[4*i+1] = v.y; nxt[4*i+2] = v.z; nxt[4*i+3] = v.w;
            }
        }
        __builtin_amdgcn_sched_barrier(0);

        float u[CH];
#pragma unroll
        for (int c = 0; c < CH; ++c) u[c] = 0.0f;

        unsigned a0 = w0, a1 = w1, a2 = w2;
        while (__ballot(a0 | a1 | a2)) {
            int p = a2 ? (95 - __clz(a2))
                       : (a1 ? (63 - __clz(a1))
                             : (a0 ? (31 - __clz(a0)) : 95));
            unsigned m = 1u << (p & 31);
            if (p >= 64)      a2 &= ~m;
            else if (p >= 32) a1 &= ~m;
            else              a0 &= ~m;

            const float* tp = &T[95 - p];
#pragma unroll
            for (int c = 0; c < CH; ++c)
                u[c] += tp[c];
        }

        float so[CH];
#pragma unroll
        for (int c = 0; c < CH; ++c) {
            const int r = c % KR;
            float u_eff = u[c] + pend[r];
            float s = (u_eff >= THETA_V) ? 1.0f : 0.0f;
#pragma unroll
            for (int i = 0; i < KR - 1; ++i)
                pend[(r + 1 + i) % KR] = fmaf(s, rt[i], pend[(r + 1 + i) % KR]);
            pend[r] = s * rt[KR - 1];
            so[c] = s;
        }

        float4* op = (float4*)(orow + ch * CH);
#pragma unroll
        for (int i = 0; i < CH / 4; ++i) {
            float4 v;
            v.x = so[4*i+0]; v.y = so[4*i+1]; v.z = so[4*i+2]; v.w = so[4*i+3];
            op[i] = v;
        }
    }
}

extern "C" void kernel_launch(void* const* d_in, const int* in_sizes, int n_in,
                              void* d_out, int out_size, void* d_ws, size_t ws_size,
                              hipStream_t stream) {
    const float* spike_in = (const float*)d_in[0];
    const float* srm      = (const float*)d_in[1];
    const float* refk     = (const float*)d_in[2];
    float* out = (float*)d_out;

    int srm_len = in_sizes[1];
    int ref_len = in_sizes[2];
    int B = in_sizes[0] / T_LEN;   // 65536 neurons

    const size_t need = (size_t)B * sizeof(unsigned);   // flags only: 256 KB

    if (d_ws != nullptr && ws_size >= need) {
        unsigned* flags = (unsigned*)d_ws;
        const int groups = (B + NPB - 1) / NPB;          // 1024
        fused_kernel<<<groups, 256, 0, stream>>>(spike_in, srm, srm_len,
                                                 out, flags, B);
        scan_fix_kernel<<<(B + 255) / 256, 256, 0, stream>>>(
            spike_in, srm, srm_len, refk, ref_len, out, flags, B);
    } else {
        int grid = (B + 255) / 256;
        spike_layer_kernel<<<grid, 256, 0, stream>>>(spike_in, srm, srm_len,
                                                     refk, ref_len, out, B);
    }
}

// Round 20
// 148.345 us; speedup vs baseline: 1.1679x; 1.0100x over previous
//
#include <hip/hip_runtime.h>

// SNN spike layer: causal alpha-PSP FIR conv (taps 1..76; srm[0]==0 exactly)
// + sequential refractory threshold scan.
//
// Round-20 = round-19 resubmitted verbatim (bench infra failed; untested).
// Attack latency exposure, not access pattern. R16/R17/R18 proved the fused
// kernel's 52us is NOT read-pattern-bound (3 different patterns, same time).
// Counters said: 1024 blocks = 4 blocks/CU, Occupancy 30%, 2 barriers x
// vmcnt(0) drains -> concurrency starvation. This build:
//   - NPB=32 -> 2048 blocks = 8 blocks/CU (2x block concurrency, LDS 12KB)
//   - phase A = loads ONLY (pack bool-bytes -> LDS); barrier waits reads
//   - zero-stores moved into phase B: threads 32..255 store zeros WHILE
//     threads 0..31 run the serial 299-step IIR -> streams overlap
//   - pack/nibble, IIR, model guard, scan_fix, fallback: unchanged/verified
//
// Exactness theorem (all inputs): srm[j] = c*j*rho^j (c=e/10, rho=e^-0.1);
// A[t]=rho*(A[t-1]+x[t-1]), D[t]=rho*D[t-1]+A[t] => c*D[t] = untruncated
// conv >= u_true[t] (all terms >= 0). Ref tail rt[] <= 0 => pend <= 0 =>
// u_eff <= u_true <= c*D. Unflagged (c*dmax < 9 < theta) => no spike =>
// zeros exact. Model guard: all 77 taps checked vs model (tol 2e-3) and
// srm_len==77; mismatch -> flag ALL -> scan_fix recomputes exactly.

#define T_LEN 300
#define CH 20
#define NCHUNK 15
#define KS 77              // srm kernel length (alpha, tau=10, eps_tol=0.01)
#define KR 10              // ref kernel tail length (K_ref=11 -> 10 pending)
#define THETA_V 10.0f
#define TSZ 115            // scan_fix gather table: idx = 95 + c - p

#define RHO_F   0.9048374180359596f   // exp(-0.1)
#define C_E10   0.2718281828459045f   // e/10
#define THR_D   (9.0f / C_E10)        // flag iff D >= 9/c
#define TAP_TOL 2e-3f

#define NPB  32            // neurons per group/block
#define WPG  300           // bit-words per group: 32*300/32
#define F4PG 2400          // float4s per group: 32*300/4
#define SW   2700          // stage u32s: 2400 + 2400/8 pad

// -------- fused: coalesced bool-byte stage + pack + IIR flag + zeros -------
__global__ __launch_bounds__(256) void fused_kernel(
    const float* __restrict__ spike_in,
    const float* __restrict__ srm, int srm_len,
    float* __restrict__ out, unsigned* __restrict__ flags, int B)
{
    __shared__ unsigned stage[SW];                // 10.8 KB bool-byte stage
    __shared__ unsigned Wlds[WPG + 8];            // 1.2 KB bit-words

    const int t = threadIdx.x;
    const int g = blockIdx.x;                     // neuron group
    const long long NF     = (long long)B * T_LEN;
    const long long base_4 = (long long)F4PG * g; // group's first float4

    // ---- phase A (loads only): lane-consecutive float4 loads, pack 4
    // bool-bytes -> 1 u32 -> LDS.  10 independent loads per thread. --------
#pragma unroll
    for (int k = 0; k < 10; ++k) {
        const int i4 = t + 256 * k;
        if (i4 < F4PG) {
            const long long f4 = base_4 + i4;
            unsigned pk = 0u;
            if (4 * f4 + 4 <= NF) {               // NF divisible by 4
                float4 v = ((const float4*)spike_in)[f4];
                pk  = (v.x != 0.0f ? 1u : 0u);
                pk |= (v.y != 0.0f ? 1u : 0u) << 8;
                pk |= (v.z != 0.0f ? 1u : 0u) << 16;
                pk |= (v.w != 0.0f ? 1u : 0u) << 24;
            }
            stage[i4 + (i4 >> 3)] = pk;           // pad/8 -> 2-way banks
        }
    }

    __syncthreads();

    // ---- pack: word w = quads 8w..8w+7 (stage idx 9w+i); nibble trick ----
    {
        const int w = t;
        if (w < WPG) {
            unsigned bits = 0u;
#pragma unroll
            for (int i = 0; i < 8; ++i) {
                unsigned v = stage[9 * w + i];
                v = (v | (v >> 7) | (v >> 14) | (v >> 21)) & 0xFu;
                bits |= v << (4 * i);
            }
            Wlds[w] = bits;
        }
        const int w2 = t + 256;
        if (w2 < WPG) {
            unsigned bits = 0u;
#pragma unroll
            for (int i = 0; i < 8; ++i) {
                unsigned v = stage[9 * w2 + i];
                v = (v | (v >> 7) | (v >> 14) | (v >> 21)) & 0xFu;
                bits |= v << (4 * i);
            }
            Wlds[w2] = bits;
        }
    }
    if (t < 8) Wlds[WPG + t] = 0u;                // funnel-read slack

    __syncthreads();

    // ---- phase B: threads 0..31 IIR; threads 32..255 zero-store (overlap) --
    if (t < NPB) {
        const long long neuron = (long long)NPB * g + t;
        if (neuron < B) {
            // model guard: srm must match c*j*rho^j within TAP_TOL.
            bool ok = (srm_len == KS);
            if (ok) {
                ok = fabsf(srm[0]) <= TAP_TOL;
                float pj = 1.0f;
                for (int j = 1; j < KS; ++j) {
                    pj *= RHO_F;
                    float mj = C_E10 * (float)j * pj;
                    ok = ok && (fabsf(srm[j] - mj) <= TAP_TOL);
                }
            }

            // assemble row bits: row t covers group bits [300t, 300t+300)
            const int F0 = T_LEN * t;
            const int q = F0 >> 5;
            const int r = F0 & 31;
            unsigned W[11];
#pragma unroll
            for (int k = 0; k < 11; ++k) W[k] = Wlds[q + k];
            unsigned aw[10];                      // aw[k] bit b = row bit 32k+b
#pragma unroll
            for (int k = 0; k < 10; ++k)
                aw[k] = (unsigned)((((unsigned long long)W[k + 1] << 32) | W[k]) >> r);

            // IIR: A[t]=rho*(A[t-1]+x[t-1]); D[t]=rho*D[t-1]+A[t]
            float A = 0.0f, D = 0.0f, dmax = 0.0f;
#pragma unroll
            for (int tt = 1; tt < T_LEN; ++tt) {
                const int bw = (tt - 1) >> 5;     // compile-time
                const int bb = (tt - 1) & 31;     // compile-time
                int ms = ((int)(aw[bw] << (31 - bb))) >> 31;
                float xr = __int_as_float(ms & __float_as_int(RHO_F));
                A = fmaf(RHO_F, A, xr);
                D = fmaf(RHO_F, D, A);
                dmax = fmaxf(dmax, D);
            }

            flags[neuron] = (!ok || (dmax >= THR_D)) ? 1u : 0u;
        }
    } else {
        // zero-store of the group's output region, coalesced, overlapped
        // with the IIR chain above (independent streams).
        const float4 z = make_float4(0.0f, 0.0f, 0.0f, 0.0f);
        const long long nf4 = NF >> 2;
        float4* o4 = (float4*)out;
        const int ts = t - NPB;                   // 0..223
#pragma unroll
        for (int k = 0; k < 11; ++k) {            // 11*224 >= 2400
            const int lw = ts + 224 * k;
            if (lw < F4PG) {
                const long long i4 = base_4 + lw;
                if (i4 < nf4) o4[i4] = z;
            }
        }
    }
}

// ------------- scan_fix: flagged rows -> verified exact recompute ----------
__global__ __launch_bounds__(256) void scan_fix_kernel(
    const float* __restrict__ spike_in,
    const float* __restrict__ srm, int srm_len,
    const float* __restrict__ refk, int ref_len,
    float* __restrict__ out, const unsigned* __restrict__ flags, int B)
{
    __shared__ float T[TSZ + 13];
    {
        int k = threadIdx.x;
        if (k < TSZ + 13) {
            int j = k - 19;
            T[k] = (j >= 1 && j < KS && j < srm_len) ? srm[j] : 0.0f;
        }
    }
    __syncthreads();

    int b = blockIdx.x * blockDim.x + threadIdx.x;
    if (b >= B) return;
    if (flags[b] == 0u) return;     // zeros from fused are exact

    const float* row  = spike_in + (size_t)b * T_LEN;
    float*       orow = out      + (size_t)b * T_LEN;

    float rt[KR];
#pragma unroll
    for (int i = 0; i < KR; ++i) rt[i] = (i + 1 < ref_len) ? refk[i + 1] : 0.0f;
    float pend[KR];
#pragma unroll
    for (int i = 0; i < KR; ++i) pend[i] = 0.0f;

    unsigned w0 = 0, w1 = 0, w2 = 0;
    float nxt[CH];
    {
        const float4* p = (const float4*)row;
#pragma unroll
        for (int i = 0; i < CH / 4; ++i) {
            float4 v = p[i];
            nxt[4*i+0] = v.x; nxt[4*i+1] = v.y; nxt[4*i+2] = v.z; nxt[4*i+3] = v.w;
        }
    }

#pragma unroll 1
    for (int ch = 0; ch < NCHUNK; ++ch) {
        unsigned nb = 0;
#pragma unroll
        for (int i = 0; i < CH; ++i)
            nb |= (nxt[i] != 0.0f) ? (1u << i) : 0u;

        w0 = (w0 >> 20) | (w1 << 12);
        w1 = (w1 >> 20) | (w2 << 12);
        w2 = (w2 >> 20) | (nb << 12);

        if (ch + 1 < NCHUNK) {
            const float4* p = (const float4*)(row + (ch + 1) * CH);
#pragma unroll
            for (int i = 0; i < CH / 4; ++i) {
                float4 v = p[i];
                nxt[4*i+0] = v.x; nxt[4*i+1] = v.y; nxt[4*i+2] = v.z; nxt[4*i+3] = v.w;
            }
        }
        __builtin_amdgcn_sched_barrier(0);

        float u[CH];
#pragma unroll
        for (int c = 0; c < CH; ++c) u[c] = 0.0f;

        unsigned a0 = w0, a1 = w1, a2 = w2;
        while (__ballot(a0 | a1 | a2)) {
            int p = a2 ? (95 - __clz(a2))
                       : (a1 ? (63 - __clz(a1))
                             : (a0 ? (31 - __clz(a0)) : 95));
            unsigned m = 1u << (p & 31);
            if (p >= 64)      a2 &= ~m;
            else if (p >= 32) a1 &= ~m;
            else              a0 &= ~m;

            const float* tp = &T[95 - p];
#pragma unroll
            for (int c = 0; c < CH; ++c)
                u[c] += tp[c];          // == fmaf(srm[j], 1.0f, u[c])
        }

        float so[CH];
#pragma unroll
        for (int c = 0; c < CH; ++c) {
            const int r = c % KR;
            float u_eff = u[c] + pend[r];
            float s = (u_eff >= THETA_V) ? 1.0f : 0.0f;
#pragma unroll
            for (int i = 0; i < KR - 1; ++i)
                pend[(r + 1 + i) % KR] = fmaf(s, rt[i], pend[(r + 1 + i) % KR]);
            pend[r] = s * rt[KR - 1];
            so[c] = s;
        }

        float4* op = (float4*)(orow + ch * CH);
#pragma unroll
        for (int i = 0; i < CH / 4; ++i) {
            float4 v;
            v.x = so[4*i+0]; v.y = so[4*i+1]; v.z = so[4*i+2]; v.w = so[4*i+3];
            op[i] = v;
        }
    }
}

// --------- fallback: round-10 single-kernel path (ws too small) ------------
__global__ __launch_bounds__(256)
__attribute__((amdgpu_waves_per_eu(1, 1)))
void spike_layer_kernel(
    const float* __restrict__ spike_in,
    const float* __restrict__ srm, int srm_len,
    const float* __restrict__ refk, int ref_len,
    float* __restrict__ out, int B)
{
    __shared__ float T[TSZ + 13];
    {
        int k = threadIdx.x;
        if (k < TSZ + 13) {
            int j = k - 19;
            T[k] = (j >= 1 && j < KS && j < srm_len) ? srm[j] : 0.0f;
        }
    }
    __syncthreads();

    int b = blockIdx.x * blockDim.x + threadIdx.x;
    if (b >= B) return;

    const float* row  = spike_in + (size_t)b * T_LEN;
    float*       orow = out      + (size_t)b * T_LEN;

    float rt[KR];
#pragma unroll
    for (int i = 0; i < KR; ++i) rt[i] = (i + 1 < ref_len) ? refk[i + 1] : 0.0f;
    float pend[KR];
#pragma unroll
    for (int i = 0; i < KR; ++i) pend[i] = 0.0f;

    unsigned w0 = 0, w1 = 0, w2 = 0;
    float nxt[CH];
    {
        const float4* p = (const float4*)row;
#pragma unroll
        for (int i = 0; i < CH / 4; ++i) {
            float4 v = p[i];
            nxt[4*i+0] = v.x; nxt[4*i+1] = v.y; nxt[4*i+2] = v.z; nxt[4*i+3] = v.w;
        }
    }

#pragma unroll 1
    for (int ch = 0; ch < NCHUNK; ++ch) {
        unsigned nb = 0;
#pragma unroll
        for (int i = 0; i < CH; ++i)
            nb |= (nxt[i] != 0.0f) ? (1u << i) : 0u;

        w0 = (w0 >> 20) | (w1 << 12);
        w1 = (w1 >> 20) | (w2 << 12);
        w2 = (w2 >> 20) | (nb << 12);

        if (ch + 1 < NCHUNK) {
            const float4* p = (const float4*)(row + (ch + 1) * CH);
#pragma unroll
            for (int i = 0; i < CH / 4; ++i) {
                float4 v = p[i];
                nxt[4*i+0] = v.x; nxt[4*i+1] = v.y; nxt[4*i+2] = v.z; nxt[4*i+3] = v.w;
            }
        }
        __builtin_amdgcn_sched_barrier(0);

        float u[CH];
#pragma unroll
        for (int c = 0; c < CH; ++c) u[c] = 0.0f;

        unsigned a0 = w0, a1 = w1, a2 = w2;
        while (__ballot(a0 | a1 | a2)) {
            int p = a2 ? (95 - __clz(a2))
                       : (a1 ? (63 - __clz(a1))
                             : (a0 ? (31 - __clz(a0)) : 95));
            unsigned m = 1u << (p & 31);
            if (p >= 64)      a2 &= ~m;
            else if (p >= 32) a1 &= ~m;
            else              a0 &= ~m;

            const float* tp = &T[95 - p];
#pragma unroll
            for (int c = 0; c < CH; ++c)
                u[c] += tp[c];
        }

        float so[CH];
#pragma unroll
        for (int c = 0; c < CH; ++c) {
            const int r = c % KR;
            float u_eff = u[c] + pend[r];
            float s = (u_eff >= THETA_V) ? 1.0f : 0.0f;
#pragma unroll
            for (int i = 0; i < KR - 1; ++i)
                pend[(r + 1 + i) % KR] = fmaf(s, rt[i], pend[(r + 1 + i) % KR]);
            pend[r] = s * rt[KR - 1];
            so[c] = s;
        }

        float4* op = (float4*)(orow + ch * CH);
#pragma unroll
        for (int i = 0; i < CH / 4; ++i) {
            float4 v;
            v.x = so[4*i+0]; v.y = so[4*i+1]; v.z = so[4*i+2]; v.w = so[4*i+3];
            op[i] = v;
        }
    }
}

extern "C" void kernel_launch(void* const* d_in, const int* in_sizes, int n_in,
                              void* d_out, int out_size, void* d_ws, size_t ws_size,
                              hipStream_t stream) {
    const float* spike_in = (const float*)d_in[0];
    const float* srm      = (const float*)d_in[1];
    const float* refk     = (const float*)d_in[2];
    float* out = (float*)d_out;

    int srm_len = in_sizes[1];
    int ref_len = in_sizes[2];
    int B = in_sizes[0] / T_LEN;   // 65536 neurons

    const size_t need = (size_t)B * sizeof(unsigned);   // flags only: 256 KB

    if (d_ws != nullptr && ws_size >= need) {
        unsigned* flags = (unsigned*)d_ws;
        const int groups = (B + NPB - 1) / NPB;          // 2048
        fused_kernel<<<groups, 256, 0, stream>>>(spike_in, srm, srm_len,
                                                 out, flags, B);
        scan_fix_kernel<<<(B + 255) / 256, 256, 0, stream>>>(
            spike_in, srm, srm_len, refk, ref_len, out, flags, B);
    } else {
        int grid = (B + 255) / 256;
        spike_layer_kernel<<<grid, 256, 0, stream>>>(spike_in, srm, srm_len,
                                                     refk, ref_len, out, B);
    }
}

// Round 21
// 147.185 us; speedup vs baseline: 1.1771x; 1.0079x over previous
//
#include <hip/hip_runtime.h>

// SNN spike layer: causal alpha-PSP FIR conv (taps 1..76; srm[0]==0 exactly)
// + sequential refractory threshold scan.
//
// Round-21: SINGLE-DISPATCH build. Ledger: totals are insensitive to fused
// duration in [52,72]us (R16/R18/R20: 149.9/149.8/148.3) but respond to
// dispatch count (R13->R14: -1 dispatch = -30us; R14->R16: -2 = -11us).
// So the last structural lever is folding scan_fix INTO the fused kernel:
//   - phase A (R18 body, fastest verified): lane-consecutive float4 loads
//     (19 independent/thread), pack bool-bytes -> LDS stage; coalesced
//     zero-store of the group's output.  __syncthreads (drains vmcnt(0)
//     before s_barrier per compiler semantics -> zero-stores complete
//     before any phase-B rewrite).
//   - pack: nibble-trick stage -> Wlds bit-words (layout verified R16/R18).
//   - phase B (threads 0..63): funnel row bits -> aw[10]; verified 299-step
//     IIR upper bound -> flag in REGISTER (no ws at all). If any lane in
//     wave 0 is flagged (wave-uniform ballot; never taken for this input
//     class), flagged lanes run the verified R10 event-driven conv +
//     sequential scan from aw[] bits + LDS T-table and rewrite their row.
// One kernel, no workspace, no second dispatch, no flags round-trip.
//
// Exactness theorem (all inputs, binary-valued as in every verified round
// since R10 -- nonzero treated as 1.0): srm[j] = c*j*rho^j (c=e/10,
// rho=e^-0.1); A[t]=rho*(A[t-1]+x[t-1]), D[t]=rho*D[t-1]+A[t] => c*D[t] =
// untruncated conv >= u_true[t] (all terms >= 0). Ref tail rt[] <= 0 =>
// pend <= 0 => u_eff <= u_true <= c*D. Unflagged (c*dmax < 9 < theta) =>
// no spike => phase-A zeros exact. Model guard: all 77 srm taps checked vs
// model (tol 2e-3) and srm_len==77; mismatch -> flag ALL rows -> in-block
// exact recompute everywhere.

#define T_LEN 300
#define CH 20
#define NCHUNK 15
#define KS 77              // srm kernel length (alpha, tau=10, eps_tol=0.01)
#define KR 10              // ref kernel tail length (K_ref=11 -> 10 pending)
#define THETA_V 10.0f
#define TSZ 115            // scan gather table: idx = 95 + c - p

#define RHO_F   0.9048374180359596f   // exp(-0.1)
#define C_E10   0.2718281828459045f   // e/10
#define THR_D   (9.0f / C_E10)        // flag iff D >= 9/c
#define TAP_TOL 2e-3f

#define NPB  64            // neurons per group/block
#define WPG  600           // bit-words per group: 64*300/32
#define F4PG 4800          // float4s per group: 64*300/4
#define SW   5400          // stage u32s: 4800 + 4800/8 pad

// ---- fused: stage + pack + zero-store + IIR flag + in-block exact fix ----
__global__ __launch_bounds__(256) void fused_kernel(
    const float* __restrict__ spike_in,
    const float* __restrict__ srm, int srm_len,
    const float* __restrict__ refk, int ref_len,
    float* __restrict__ out, int B)
{
    __shared__ unsigned stage[SW];                // 21.6 KB bool-byte stage
    __shared__ unsigned Wlds[WPG + 8];            // 2.4 KB bit-words
    __shared__ float    T[128];                   // scan gather table

    const int t = threadIdx.x;
    const int g = blockIdx.x;                     // neuron group
    const long long NF     = (long long)B * T_LEN;
    const long long base_4 = (long long)F4PG * g; // group's first float4

    // T table: T[k] = srm[k-19] iff 1 <= k-19 <= 76, else exact 0
    if (t < 128) {
        int j = t - 19;
        T[t] = (j >= 1 && j < KS && j < srm_len) ? srm[j] : 0.0f;
    }

    // ---- phase A: lane-consecutive float4 loads (1KB/instr coalesced),
    // 19 independent per thread; pack 4 bool-bytes -> 1 u32 -> LDS. --------
#pragma unroll
    for (int k = 0; k < 19; ++k) {
        const int i4 = t + 256 * k;
        if (i4 < F4PG) {
            const long long f4 = base_4 + i4;
            unsigned pk = 0u;
            if (4 * f4 + 4 <= NF) {               // NF divisible by 4
                float4 v = ((const float4*)spike_in)[f4];
                pk  = (v.x != 0.0f ? 1u : 0u);
                pk |= (v.y != 0.0f ? 1u : 0u) << 8;
                pk |= (v.z != 0.0f ? 1u : 0u) << 16;
                pk |= (v.w != 0.0f ? 1u : 0u) << 24;
            }
            stage[i4 + (i4 >> 3)] = pk;           // pad/8 -> 2-way banks
        }
    }

    // ---- phase A: coalesced zero-store of the group's output region.
    // Exact for unflagged rows; flagged rows rewritten in phase B (the
    // barrier's vmcnt(0) drain orders these stores before the rewrite). ----
    {
        const float4 z = make_float4(0.0f, 0.0f, 0.0f, 0.0f);
        const long long nf4 = NF >> 2;
        float4* o4 = (float4*)out;
#pragma unroll
        for (int k = 0; k < 19; ++k) {            // 19*256 >= 4800
            const int lw = t + 256 * k;
            if (lw < F4PG) {
                const long long i4 = base_4 + lw;
                if (i4 < nf4) o4[i4] = z;
            }
        }
    }

    __syncthreads();

    // ---- pack: word w = quads 8w..8w+7 (stage idx 9w+i); nibble trick ----
#pragma unroll
    for (int k = 0; k < 3; ++k) {
        const int w = t + 256 * k;
        if (w < WPG) {
            unsigned bits = 0u;
#pragma unroll
            for (int i = 0; i < 8; ++i) {
                unsigned v = stage[9 * w + i];    // bank (9w+i)%32: 2-way
                v = (v | (v >> 7) | (v >> 14) | (v >> 21)) & 0xFu;
                bits |= v << (4 * i);
            }
            Wlds[w] = bits;                       // layout verified R16/R18
        }
    }
    if (t < 8) Wlds[WPG + t] = 0u;                // funnel-read slack

    __syncthreads();

    // ---- phase B: wave 0, one thread per neuron ---------------------------
    if (t >= NPB) return;

    const long long neuron = (long long)NPB * g + t;
    const bool valid = (neuron < B);

    // model guard: srm must match c*j*rho^j within TAP_TOL (uniform work).
    bool ok = (srm_len == KS);
    if (ok) {
        ok = fabsf(srm[0]) <= TAP_TOL;
        float pj = 1.0f;
        for (int j = 1; j < KS; ++j) {
            pj *= RHO_F;
            float mj = C_E10 * (float)j * pj;
            ok = ok && (fabsf(srm[j] - mj) <= TAP_TOL);
        }
    }

    // assemble row bits: row t covers group bits [300t, 300t+300)
    const int F0 = T_LEN * t;
    const int q = F0 >> 5;
    const int r = F0 & 31;
    unsigned W[11];
#pragma unroll
    for (int k = 0; k < 11; ++k) W[k] = Wlds[q + k];
    unsigned aw2[11];                 // aw2[k] bit b = row bit 32k+b; [10]=0
#pragma unroll
    for (int k = 0; k < 10; ++k)
        aw2[k] = (unsigned)((((unsigned long long)W[k + 1] << 32) | W[k]) >> r);
    aw2[10] = 0u;

    // IIR upper bound (verified): A[t]=rho*(A[t-1]+x[t-1]); D=rho*D+A
    float A = 0.0f, D = 0.0f, dmax = 0.0f;
#pragma unroll
    for (int tt = 1; tt < T_LEN; ++tt) {
        const int bw = (tt - 1) >> 5;             // compile-time
        const int bb = (tt - 1) & 31;             // compile-time
        int ms = ((int)(aw2[bw] << (31 - bb))) >> 31;
        float xr = __int_as_float(ms & __float_as_int(RHO_F));
        A = fmaf(RHO_F, A, xr);
        D = fmaf(RHO_F, D, A);
        dmax = fmaxf(dmax, D);
    }

    const bool fire_row = valid && (!ok || (dmax >= THR_D));

    // wave-uniform skip: normally no lane is flagged -> exit immediately
    if (__ballot(fire_row) == 0ull) return;

    // ---- in-block exact fix-up (verified R10 scan; bits are exact for
    // binary input -- the assumption of every verified round since R10) ----
    float rt[KR];
#pragma unroll
    for (int i = 0; i < KR; ++i) rt[i] = (i + 1 < ref_len) ? refk[i + 1] : 0.0f;
    float pend[KR];
#pragma unroll
    for (int i = 0; i < KR; ++i) pend[i] = 0.0f;

    float* orow = out + (size_t)neuron * T_LEN;
    unsigned w0s = 0u, w1s = 0u, w2s = 0u;

#pragma unroll
    for (int ch = 0; ch < NCHUNK; ++ch) {
        // chunk bits [20ch, 20ch+20) from aw2 (compile-time word/shift)
        const int bp = 20 * ch, qw = bp >> 5, rr = bp & 31;
        unsigned nb = fire_row
            ? ((unsigned)((((unsigned long long)aw2[qw + 1] << 32) | aw2[qw]) >> rr)
               & 0xFFFFFu)
            : 0u;                                  // idle lanes: empty masks

        w0s = (w0s >> 20) | (w1s << 12);
        w1s = (w1s >> 20) | (w2s << 12);
        w2s = (w2s >> 20) | (nb << 12);

        float u[CH];
#pragma unroll
        for (int c = 0; c < CH; ++c) u[c] = 0.0f;

        unsigned a0 = w0s, a1 = w1s, a2 = w2s;
        while (__ballot(a0 | a1 | a2)) {
            int p = a2 ? (95 - __clz(a2))
                       : (a1 ? (63 - __clz(a1))
                             : (a0 ? (31 - __clz(a0)) : 95));
            unsigned m = 1u << (p & 31);
            if (p >= 64)      a2 &= ~m;
            else if (p >= 32) a1 &= ~m;
            else              a0 &= ~m;

            const float* tp = &T[95 - p];
#pragma unroll
            for (int c = 0; c < CH; ++c)
                u[c] += tp[c];          // == fmaf(srm[j], 1.0f, u[c])
        }

        float so[CH];
#pragma unroll
        for (int c = 0; c < CH; ++c) {
            const int rr2 = c % KR;     // compile-time (CH == 2*KR)
            float u_eff = u[c] + pend[rr2];
            float s = (u_eff >= THETA_V) ? 1.0f : 0.0f;
#pragma unroll
            for (int i = 0; i < KR - 1; ++i)
                pend[(rr2 + 1 + i) % KR] = fmaf(s, rt[i], pend[(rr2 + 1 + i) % KR]);
            pend[rr2] = s * rt[KR - 1]; // consumed slot becomes logical tail
            so[c] = s;
        }

        if (fire_row) {
            float4* op = (float4*)(orow + ch * CH);
#pragma unroll
            for (int i = 0; i < CH / 4; ++i) {
                float4 v;
                v.x = so[4*i+0]; v.y = so[4*i+1]; v.z = so[4*i+2]; v.w = so[4*i+3];
                op[i] = v;
            }
        }
    }
}

extern "C" void kernel_launch(void* const* d_in, const int* in_sizes, int n_in,
                              void* d_out, int out_size, void* d_ws, size_t ws_size,
                              hipStream_t stream) {
    const float* spike_in = (const float*)d_in[0];
    const float* srm      = (const float*)d_in[1];
    const float* refk     = (const float*)d_in[2];
    float* out = (float*)d_out;

    int srm_len = in_sizes[1];
    int ref_len = in_sizes[2];
    int B = in_sizes[0] / T_LEN;   // 65536 neurons

    const int groups = (B + NPB - 1) / NPB;        // 1024 blocks
    fused_kernel<<<groups, 256, 0, stream>>>(spike_in, srm, srm_len,
                                             refk, ref_len, out, B);
}